// Round 12
// baseline (790.446 us; speedup 1.0000x reference)
//
#include <hip/hip_runtime.h>
#include <math.h>

// Problem constants: B=8, CIN=3, COUT=16, H=W=384
#define BQ   8
#define CIN  3
#define COUT 16
#define HW   (384 * 384)            // 147456
#define NPIX (BQ * HW)              // 1,179,648 pixels
#define NELT 18874368.0f            // NPIX * COUT
#define MAX_ITERS 16

#define TPB       256
#define BPC       2                 // 2 blocks/CU (barrier co-residency; LDS 64KB/block)
#define NBLK      (BPC * 256)       // 512 blocks
#define NTHREADS  (NBLK * TPB)      // 131,072
#define PPT       9                 // 9 pixels/thread: 5 in registers + 4 in LDS

#define NREG 5                      // pixels resident in VGPRs (80 floats)
#define NLDS 4                      // pixels resident in LDS (64 KB/block)

#define SCOPE_AGENT __HIP_MEMORY_SCOPE_AGENT

typedef float vfloat16 __attribute__((ext_vector_type(16)));

// Flat barrier state: ONE cache line, zeroed by hipMemsetAsync (no k_init).
// sense is monotonic (round<<1 | stop), so 0 = "before round 1".
struct __align__(64) Ctl { int cnt; float acc; int sense; int pad[13]; };

// tanh(x) = 1 - 2/(exp(2x)+1): v_exp_f32 + v_rcp_f32, ~6 instrs, ~1e-7 abs err.
__device__ __forceinline__ float tanh_fast(float x) {
    float e = __expf(2.0f * x);
    return fmaf(-2.0f, __builtin_amdgcn_rcpf(e + 1.0f), 1.0f);
}

// Completion fence for agent-scope atomics (they execute at the LLC).
__device__ __forceinline__ void vm_drain() {
    asm volatile("s_waitcnt vmcnt(0)" ::: "memory");
}

// block = 256 threads = 4 waves; full block sum returned on tid 0
__device__ __forceinline__ float block_reduce_add(float v) {
    #pragma unroll
    for (int off = 32; off > 0; off >>= 1)
        v += __shfl_down(v, off, 64);
    __shared__ float red[TPB / 64];
    int lane = threadIdx.x & 63;
    int wid  = threadIdx.x >> 6;
    if (lane == 0) red[wid] = v;
    __syncthreads();
    float r = 0.f;
    if (threadIdx.x == 0) {
        #pragma unroll
        for (int i = 0; i < TPB / 64; ++i) r += red[i];
    }
    return r;
}

// FLAT fused reduction + barrier + central uniform decision (R9-proven).
__device__ __forceinline__ int arrive_and_decide(Ctl* c, float v, int round,
                                                 int* stop_sh) {
    float r = block_reduce_add(v);
    if (threadIdx.x == 0) {
        __hip_atomic_fetch_add(&c->acc, r, __ATOMIC_RELAXED, SCOPE_AGENT);
        vm_drain();                                   // acc landed before cnt
        int p = __hip_atomic_fetch_add(&c->cnt, 1, __ATOMIC_RELAXED,
                                       SCOPE_AGENT);
        if (p == NBLK - 1) {
            float total = __hip_atomic_exchange(&c->acc, 0.0f,
                                                __ATOMIC_RELAXED, SCOPE_AGENT);
            __hip_atomic_exchange(&c->cnt, 0, __ATOMIC_RELAXED, SCOPE_AGENT);
            vm_drain();                               // resets done before publish
            int stop = (total >= 3.0f * NELT) ? 1 : 0;
            __hip_atomic_store(&c->sense, (round << 1) | stop,
                               __ATOMIC_RELEASE, SCOPE_AGENT);
        }
        int s;
        for (;;) {
            s = __hip_atomic_load(&c->sense, __ATOMIC_ACQUIRE, SCOPE_AGENT);
            if ((s >> 1) >= round) break;
            __builtin_amdgcn_s_sleep(2);
        }
        *stop_sh = s & 1;
    }
    __syncthreads();
    return *stop_sh;
}

// ---- R9's exact per-pixel bodies (unrolled, s_load weights) ----

#define PRE_PIXEL(vk, kk)                                                \
    { int p = tid + (kk) * NTHREADS; int b = p / HW; int hw = p - b * HW;\
      const float* xb = x + (size_t)b * (CIN * HW) + hw;                 \
      float x0 = xb[0], x1 = xb[HW], x2 = xb[2 * HW];                    \
      _Pragma("unroll")                                                  \
      for (int o = 0; o < COUT; ++o) {                                   \
          float a = bp[o];                                               \
          a = fmaf(wp[o * CIN + 0], x0, a);                              \
          a = fmaf(wp[o * CIN + 1], x1, a);                              \
          a = fmaf(wp[o * CIN + 2], x2, a);                              \
          vk[o] = a; s += fabsf(a);                                      \
      } }

#define STEP_PIXEL(vk)                                                   \
    { float tt[COUT];                                                    \
      _Pragma("unroll")                                                  \
      for (int o = 0; o < COUT; ++o) {                                   \
          float a = bs[o];                                               \
          _Pragma("unroll")                                              \
          for (int c = 0; c < COUT; ++c)                                 \
              a = fmaf(ws[o * COUT + c], vk[c], a);                      \
          tt[o] = tanh_fast(a);                                          \
      }                                                                  \
      _Pragma("unroll")                                                  \
      for (int o = 0; o < COUT; ++o) {                                   \
          float a = bl[o];                                               \
          _Pragma("unroll")                                              \
          for (int c = 0; c < COUT; ++c)                                 \
              a = fmaf(wl[o * COUT + c], tt[c], a);                      \
          a *= 10.f;                                                     \
          vk[o] = a; s += fabsf(a);                                      \
      } }

#define FIN_PIXEL(vk, kk)                                                \
    { int p = tid + (kk) * NTHREADS; int b = p / HW; int hw = p - b * HW;\
      float* ob = out + (size_t)b * (COUT * HW) + hw;                    \
      _Pragma("unroll")                                                  \
      for (int o = 0; o < COUT; ++o) {                                   \
          float a = bs[o];                                               \
          _Pragma("unroll")                                              \
          for (int c = 0; c < COUT; ++c)                                 \
              a = fmaf(ws[o * COUT + c], vk[c], a);                      \
          ob[(size_t)o * HW] = a;                                        \
      } }

// ---- LDS state staging: [px][c][thread] -> lane-stride-1 (2-way aliasing,
// free per bank rules); per-thread channel stride 1 KB -> ds ops with
// compile-time offsets, all within the 16-bit immediate.
#define LDS_LOAD(tv, px)                                                 \
    _Pragma("unroll")                                                    \
    for (int c = 0; c < COUT; ++c) tv[c] = lds_state[px][c][t];
#define LDS_STORE(tv, px)                                                \
    _Pragma("unroll")                                                    \
    for (int c = 0; c < COUT; ++c) lds_state[px][c][t] = tv[c];

__global__ __launch_bounds__(TPB, BPC) void k_persist(
        const float* __restrict__ x,
        const float* __restrict__ wp, const float* __restrict__ bp,
        const float* __restrict__ wl, const float* __restrict__ bl,
        const float* __restrict__ ws, const float* __restrict__ bs,
        float* __restrict__ out, Ctl* __restrict__ ctl) {
    __shared__ int stop_sh;
    // 4 pixels' persistent state lives in LDS (private per-thread slots; no
    // cross-thread sharing -> no extra barriers). 64 KB/block; 2 blocks/CU.
    __shared__ float lds_state[NLDS][COUT][TPB];

    const int t = threadIdx.x;
    const int tid = blockIdx.x * TPB + t;

    // Hot register state: 5 pixels = 80 floats. Total hot-live ~125 <= 128
    // arch VGPRs -> no AGPR shuttling around the FMA stream (the theory
    // this round tests).
    vfloat16 v0, v1, v2, v3, v4;

    // ---- pre conv + |v| partial
    float s = 0.f;
    PRE_PIXEL(v0, 0) PRE_PIXEL(v1, 1) PRE_PIXEL(v2, 2)
    PRE_PIXEL(v3, 3) PRE_PIXEL(v4, 4)
    {
        vfloat16 tv;
        PRE_PIXEL(tv, 5) LDS_STORE(tv, 0)
    }
    {
        vfloat16 tv;
        PRE_PIXEL(tv, 6) LDS_STORE(tv, 1)
    }
    {
        vfloat16 tv;
        PRE_PIXEL(tv, 7) LDS_STORE(tv, 2)
    }
    {
        vfloat16 tv;
        PRE_PIXEL(tv, 8) LDS_STORE(tv, 3)
    }

    int round = 1;
    int stop = arrive_and_decide(ctl, s, round, &stop_sh);

    // ---- while (mean|v| < 3): v = 10*(wl @ tanh(ws @ v + bs) + bl)
    int it = 0;
    while (!stop && it < MAX_ITERS) {
        s = 0.f;
        STEP_PIXEL(v0) STEP_PIXEL(v1) STEP_PIXEL(v2)
        STEP_PIXEL(v3) STEP_PIXEL(v4)
        {
            vfloat16 tv;
            LDS_LOAD(tv, 0) STEP_PIXEL(tv) LDS_STORE(tv, 0)
        }
        {
            vfloat16 tv;
            LDS_LOAD(tv, 1) STEP_PIXEL(tv) LDS_STORE(tv, 1)
        }
        {
            vfloat16 tv;
            LDS_LOAD(tv, 2) STEP_PIXEL(tv) LDS_STORE(tv, 2)
        }
        {
            vfloat16 tv;
            LDS_LOAD(tv, 3) STEP_PIXEL(tv) LDS_STORE(tv, 3)
        }
        ++it; ++round;
        stop = arrive_and_decide(ctl, s, round, &stop_sh);
    }

    // ---- final conv
    FIN_PIXEL(v0, 0) FIN_PIXEL(v1, 1) FIN_PIXEL(v2, 2)
    FIN_PIXEL(v3, 3) FIN_PIXEL(v4, 4)
    {
        vfloat16 tv;
        LDS_LOAD(tv, 0) FIN_PIXEL(tv, 5)
    }
    {
        vfloat16 tv;
        LDS_LOAD(tv, 1) FIN_PIXEL(tv, 6)
    }
    {
        vfloat16 tv;
        LDS_LOAD(tv, 2) FIN_PIXEL(tv, 7)
    }
    {
        vfloat16 tv;
        LDS_LOAD(tv, 3) FIN_PIXEL(tv, 8)
    }
}

extern "C" void kernel_launch(void* const* d_in, const int* in_sizes, int n_in,
                              void* d_out, int out_size, void* d_ws, size_t ws_size,
                              hipStream_t stream) {
    // dict order: x, w_pre, b_pre, w_loop, b_loop, w_shared, b_shared
    const float* x  = (const float*)d_in[0];
    const float* wp = (const float*)d_in[1];
    const float* bp = (const float*)d_in[2];
    const float* wl = (const float*)d_in[3];
    const float* bl = (const float*)d_in[4];
    const float* ws = (const float*)d_in[5];
    const float* bs = (const float*)d_in[6];
    float* out = (float*)d_out;
    Ctl*   ctl = (Ctl*)d_ws;

    // Zero the 64-byte barrier line with a DMA packet (no kernel launch).
    hipMemsetAsync(ctl, 0, sizeof(Ctl), stream);
    k_persist<<<NBLK, TPB, 0, stream>>>(x, wp, bp, wl, bl, ws, bs, out, ctl);
}

// Round 13
// 417.378 us; speedup vs baseline: 1.8938x; 1.8938x over previous
//
#include <hip/hip_runtime.h>
#include <math.h>

// Problem constants: B=8, CIN=3, COUT=16, H=W=384
#define BQ   8
#define CIN  3
#define COUT 16
#define HW   (384 * 384)            // 147456
#define NPIX (BQ * HW)              // 1,179,648 pixels
#define NELT 18874368.0f            // NPIX * COUT
#define MAX_ITERS 16

#define TPB       256
#define BPC       2                 // 2 blocks/CU: the PROVEN zero-spill budget (256 reg/wave)
#define NBLK      (BPC * 256)       // 512 blocks, co-resident by construction
#define NTHREADS  (NBLK * TPB)      // 131,072
#define PPT       9                 // 131,072 * 9 == NPIX exactly; 144 state floats/thread

#define SCOPE_AGENT __HIP_MEMORY_SCOPE_AGENT

typedef float vfloat16 __attribute__((ext_vector_type(16)));

// Flat barrier state: ONE cache line, zeroed by hipMemsetAsync (no k_init).
// sense is monotonic (round<<1 | stop), so 0 = "before round 1".
struct __align__(64) Ctl { int cnt; float acc; int sense; int pad[13]; };

// tanh(x) = 1 - 2/(exp(2x)+1): v_exp_f32 + v_rcp_f32, ~6 instrs, ~1e-7 abs err.
__device__ __forceinline__ float tanh_fast(float x) {
    float e = __expf(2.0f * x);
    return fmaf(-2.0f, __builtin_amdgcn_rcpf(e + 1.0f), 1.0f);
}

// Completion fence for agent-scope atomics (they execute at the LLC):
// draining vmcnt orders RMW pairs without any cache maintenance.
__device__ __forceinline__ void vm_drain() {
    asm volatile("s_waitcnt vmcnt(0)" ::: "memory");
}

// block = 256 threads = 4 waves; full block sum returned on tid 0
__device__ __forceinline__ float block_reduce_add(float v) {
    #pragma unroll
    for (int off = 32; off > 0; off >>= 1)
        v += __shfl_down(v, off, 64);
    __shared__ float red[TPB / 64];
    int lane = threadIdx.x & 63;
    int wid  = threadIdx.x >> 6;
    if (lane == 0) red[wid] = v;
    __syncthreads();
    float r = 0.f;
    if (threadIdx.x == 0) {
        #pragma unroll
        for (int i = 0; i < TPB / 64; ++i) r += red[i];
    }
    return r;
}

// FLAT fused reduction + barrier + central uniform decision (R9-proven).
// Same-line LLC atomics pipeline; critical path = one RMW round-trip + publish.
// Each block drains its acc-add before its cnt-add, so cnt==NBLK-1 implies all
// acc-adds landed. Resets drain before the RELEASE publish; spinners ACQUIRE.
__device__ __forceinline__ int arrive_and_decide(Ctl* c, float v, int round,
                                                 int* stop_sh) {
    float r = block_reduce_add(v);
    if (threadIdx.x == 0) {
        __hip_atomic_fetch_add(&c->acc, r, __ATOMIC_RELAXED, SCOPE_AGENT);
        vm_drain();                                   // acc landed before cnt
        int p = __hip_atomic_fetch_add(&c->cnt, 1, __ATOMIC_RELAXED,
                                       SCOPE_AGENT);
        if (p == NBLK - 1) {
            float total = __hip_atomic_exchange(&c->acc, 0.0f,
                                                __ATOMIC_RELAXED, SCOPE_AGENT);
            __hip_atomic_exchange(&c->cnt, 0, __ATOMIC_RELAXED, SCOPE_AGENT);
            vm_drain();                               // resets done before publish
            int stop = (total >= 3.0f * NELT) ? 1 : 0;
            __hip_atomic_store(&c->sense, (round << 1) | stop,
                               __ATOMIC_RELEASE, SCOPE_AGENT);
        }
        int s;
        for (;;) {
            s = __hip_atomic_load(&c->sense, __ATOMIC_ACQUIRE, SCOPE_AGENT);
            if ((s >> 1) >= round) break;
            __builtin_amdgcn_s_sleep(2);
        }
        *stop_sh = s & 1;
    }
    __syncthreads();
    return *stop_sh;
}

// ---- per-pixel macros over NAMED ext-vectors (no arrays -> guaranteed SROA).
// R0's exact scalar step: proven cleanest counters (FETCH 12.5 MB, WRITE 83 MB,
// zero spill at 2 blocks/CU).

#define PRE_PIXEL(vk, kk)                                                \
    { int p = tid + (kk) * NTHREADS; int b = p / HW; int hw = p - b * HW;\
      const float* xb = x + (size_t)b * (CIN * HW) + hw;                 \
      float x0 = xb[0], x1 = xb[HW], x2 = xb[2 * HW];                    \
      _Pragma("unroll")                                                  \
      for (int o = 0; o < COUT; ++o) {                                   \
          float a = bp[o];                                               \
          a = fmaf(wp[o * CIN + 0], x0, a);                              \
          a = fmaf(wp[o * CIN + 1], x1, a);                              \
          a = fmaf(wp[o * CIN + 2], x2, a);                              \
          vk[o] = a; s += fabsf(a);                                      \
      } }

#define STEP_PIXEL(vk)                                                   \
    { float tt[COUT];                                                    \
      _Pragma("unroll")                                                  \
      for (int o = 0; o < COUT; ++o) {                                   \
          float a = bs[o];                                               \
          _Pragma("unroll")                                              \
          for (int c = 0; c < COUT; ++c)                                 \
              a = fmaf(ws[o * COUT + c], vk[c], a);                      \
          tt[o] = tanh_fast(a);                                          \
      }                                                                  \
      _Pragma("unroll")                                                  \
      for (int o = 0; o < COUT; ++o) {                                   \
          float a = bl[o];                                               \
          _Pragma("unroll")                                              \
          for (int c = 0; c < COUT; ++c)                                 \
              a = fmaf(wl[o * COUT + c], tt[c], a);                      \
          a *= 10.f;                                                     \
          vk[o] = a; s += fabsf(a);                                      \
      } }

#define FIN_PIXEL(vk, kk)                                                \
    { int p = tid + (kk) * NTHREADS; int b = p / HW; int hw = p - b * HW;\
      float* ob = out + (size_t)b * (COUT * HW) + hw;                    \
      _Pragma("unroll")                                                  \
      for (int o = 0; o < COUT; ++o) {                                   \
          float a = bs[o];                                               \
          _Pragma("unroll")                                              \
          for (int c = 0; c < COUT; ++c)                                 \
              a = fmaf(ws[o * COUT + c], vk[c], a);                      \
          ob[(size_t)o * HW] = a;                                        \
      } }

__global__ __launch_bounds__(TPB, BPC) void k_persist(
        const float* __restrict__ x,
        const float* __restrict__ wp, const float* __restrict__ bp,
        const float* __restrict__ wl, const float* __restrict__ bl,
        const float* __restrict__ ws, const float* __restrict__ bs,
        float* __restrict__ out, Ctl* __restrict__ ctl) {
    __shared__ int stop_sh;
    const int t = threadIdx.x;
    const int tid = blockIdx.x * TPB + t;

    // State: 9 named 16-wide vectors = 144 registers. No runtime indexing.
    vfloat16 v0, v1, v2, v3, v4, v5, v6, v7, v8;

    // ---- pre conv + |v| partial
    float s = 0.f;
    PRE_PIXEL(v0, 0) PRE_PIXEL(v1, 1) PRE_PIXEL(v2, 2)
    PRE_PIXEL(v3, 3) PRE_PIXEL(v4, 4) PRE_PIXEL(v5, 5)
    PRE_PIXEL(v6, 6) PRE_PIXEL(v7, 7) PRE_PIXEL(v8, 8)

    int round = 1;
    int stop = arrive_and_decide(ctl, s, round, &stop_sh);

    // ---- while (mean|v| < 3): v = 10*(wl @ tanh(ws @ v + bs) + bl)
    int it = 0;
    while (!stop && it < MAX_ITERS) {
        s = 0.f;
        STEP_PIXEL(v0) STEP_PIXEL(v1) STEP_PIXEL(v2)
        STEP_PIXEL(v3) STEP_PIXEL(v4) STEP_PIXEL(v5)
        STEP_PIXEL(v6) STEP_PIXEL(v7) STEP_PIXEL(v8)
        ++it; ++round;
        stop = arrive_and_decide(ctl, s, round, &stop_sh);
    }

    // ---- final conv
    FIN_PIXEL(v0, 0) FIN_PIXEL(v1, 1) FIN_PIXEL(v2, 2)
    FIN_PIXEL(v3, 3) FIN_PIXEL(v4, 4) FIN_PIXEL(v5, 5)
    FIN_PIXEL(v6, 6) FIN_PIXEL(v7, 7) FIN_PIXEL(v8, 8)
}

extern "C" void kernel_launch(void* const* d_in, const int* in_sizes, int n_in,
                              void* d_out, int out_size, void* d_ws, size_t ws_size,
                              hipStream_t stream) {
    // dict order: x, w_pre, b_pre, w_loop, b_loop, w_shared, b_shared
    const float* x  = (const float*)d_in[0];
    const float* wp = (const float*)d_in[1];
    const float* bp = (const float*)d_in[2];
    const float* wl = (const float*)d_in[3];
    const float* bl = (const float*)d_in[4];
    const float* ws = (const float*)d_in[5];
    const float* bs = (const float*)d_in[6];
    float* out = (float*)d_out;
    Ctl*   ctl = (Ctl*)d_ws;

    // Zero the 64-byte barrier line with a DMA packet instead of a kernel
    // launch (graph-capture-safe; saves one dispatch per replay).
    hipMemsetAsync(ctl, 0, sizeof(Ctl), stream);
    k_persist<<<NBLK, TPB, 0, stream>>>(x, wp, bp, wl, bl, ws, bs, out, ctl);
}